// Round 3
// baseline (4744.122 us; speedup 1.0000x reference)
//
#include <hip/hip_runtime.h>
#include <hip/hip_bf16.h>
#include <math.h>

// Problem constants (fixed by reference setup_inputs)
#define T_STEPS 1024
#define BATCH   256
#define E       128
#define K2E     256   // 2*E (input feature dim)
#define G4E     512   // 4*E (gates)

typedef float  v2f    __attribute__((ext_vector_type(2)));
typedef float  f32x4  __attribute__((ext_vector_type(4)));
typedef __bf16 bf16x8 __attribute__((ext_vector_type(8)));

// ---------- math helpers ----------
__device__ __forceinline__ float sigmoidf_fast(float x) {
    return 1.0f / (1.0f + __expf(-x));
}
__device__ __forceinline__ float tanhf_fast(float x) {
    return 1.0f - 2.0f / (1.0f + __expf(2.0f * x));
}
__device__ __forceinline__ float softplusf(float x) {
    return fmaxf(x, 0.0f) + log1pf(__expf(-fabsf(x)));
}
__device__ __forceinline__ unsigned short f2bf_bits(float f) {
    __bf16 b = (__bf16)f;                       // RNE
    return __builtin_bit_cast(unsigned short, b);
}
__device__ __forceinline__ float bfbits2f(unsigned short u) {
    return __builtin_bit_cast(float, ((unsigned)u) << 16);
}

// ---------- Phase 1: x_proj GEMM (f32, packed-FMA) ----------
// xp[m,g] = sum_k x[m,k]*Wih[g,k] + (bih[g]+bhh[g]);  M=262144, K=256, N=512.
// 128x128 tile, 256 threads, 8x8 micro-tile (rows/cols split 4+4 at +64).
// Inner loop uses float2 packed FMA (v_pk_fma_f32, 314 TF ceiling).
__global__ __launch_bounds__(256, 3)
void xproj_gemm(const float* __restrict__ x, const float* __restrict__ Wih,
                const float* __restrict__ bih, const float* __restrict__ bhh,
                float* __restrict__ xp)
{
    // transposed-staged tiles [k][m]/[k][n]; 128 -> 132 pad keeps 16B alignment
    __shared__ float As[32][132];
    __shared__ float Bs[32][132];

    const int n0  = blockIdx.x * 128;
    const int m0  = blockIdx.y * 128;
    const int tid = threadIdx.x;
    const int tx  = tid & 15;          // micro col group (0..15)
    const int ty  = tid >> 4;          // micro row group (0..15)
    const int lc  = tid & 7;           // staging float4 col
    const int lr  = tid >> 3;          // staging row 0..31

    v2f acc[8][4];
    #pragma unroll
    for (int i = 0; i < 8; ++i)
        #pragma unroll
        for (int jj = 0; jj < 4; ++jj) acc[i][jj] = (v2f)0.0f;

    for (int k0 = 0; k0 < K2E; k0 += 32) {
        #pragma unroll
        for (int rr = 0; rr < 4; ++rr) {
            const int r = lr + rr * 32;
            const float4 av = *reinterpret_cast<const float4*>(
                &x[(size_t)(m0 + r) * K2E + k0 + lc * 4]);
            const float4 bv = *reinterpret_cast<const float4*>(
                &Wih[(size_t)(n0 + r) * K2E + k0 + lc * 4]);
            As[lc * 4 + 0][r] = av.x;
            As[lc * 4 + 1][r] = av.y;
            As[lc * 4 + 2][r] = av.z;
            As[lc * 4 + 3][r] = av.w;
            Bs[lc * 4 + 0][r] = bv.x;
            Bs[lc * 4 + 1][r] = bv.y;
            Bs[lc * 4 + 2][r] = bv.z;
            Bs[lc * 4 + 3][r] = bv.w;
        }
        __syncthreads();

        #pragma unroll
        for (int kk = 0; kk < 32; ++kk) {
            const f32x4 a0 = *reinterpret_cast<const f32x4*>(&As[kk][ty * 4]);
            const f32x4 a1 = *reinterpret_cast<const f32x4*>(&As[kk][64 + ty * 4]);
            const f32x4 b0 = *reinterpret_cast<const f32x4*>(&Bs[kk][tx * 4]);
            const f32x4 b1 = *reinterpret_cast<const f32x4*>(&Bs[kk][64 + tx * 4]);
            const v2f bb0 = {b0.x, b0.y}, bb1 = {b0.z, b0.w};
            const v2f bb2 = {b1.x, b1.y}, bb3 = {b1.z, b1.w};
            #pragma unroll
            for (int i = 0; i < 8; ++i) {
                const float a = (i < 4) ? a0[i] : a1[i - 4];
                const v2f av = {a, a};
                acc[i][0] = __builtin_elementwise_fma(av, bb0, acc[i][0]);
                acc[i][1] = __builtin_elementwise_fma(av, bb1, acc[i][1]);
                acc[i][2] = __builtin_elementwise_fma(av, bb2, acc[i][2]);
                acc[i][3] = __builtin_elementwise_fma(av, bb3, acc[i][3]);
            }
        }
        __syncthreads();
    }

    float bsum[8];
    #pragma unroll
    for (int jj = 0; jj < 4; ++jj) {
        bsum[jj]     = bih[n0 + tx * 4 + jj]      + bhh[n0 + tx * 4 + jj];
        bsum[4 + jj] = bih[n0 + 64 + tx * 4 + jj] + bhh[n0 + 64 + tx * 4 + jj];
    }

    #pragma unroll
    for (int i = 0; i < 8; ++i) {
        const size_t row = (size_t)(m0 + ((i < 4) ? (ty * 4 + i) : (64 + ty * 4 + i - 4)));
        float4 v0, v1;
        v0.x = acc[i][0][0] + bsum[0];
        v0.y = acc[i][0][1] + bsum[1];
        v0.z = acc[i][1][0] + bsum[2];
        v0.w = acc[i][1][1] + bsum[3];
        v1.x = acc[i][2][0] + bsum[4];
        v1.y = acc[i][2][1] + bsum[5];
        v1.z = acc[i][3][0] + bsum[6];
        v1.w = acc[i][3][1] + bsum[7];
        *reinterpret_cast<float4*>(&xp[row * G4E + n0 + tx * 4])      = v0;
        *reinterpret_cast<float4*>(&xp[row * G4E + n0 + 64 + tx * 4]) = v1;
    }
}

// ---------- Phase 2: recurrence via MFMA ----------
// 16 blocks x 16 batch. 8 waves; wave w owns hidden range j in [16w,16w+16).
// Its 4 n-tiles are the i/f/g/o tiles of that SAME j-range, so the full gate
// set for (batch row, j) is lane-local after MFMA (no gate LDS round-trip).
// W_hh fragments (bf16 hi+lo split) live in VGPRs for the whole kernel.
// h round-trips via 16KB double-buffered LDS, rotation-swizzled (read hits
// the structural 8-cyc b128 minimum); c stays in registers.
// 3-product split MFMA: h.W = Ahi*Whi + Ahi*Wlo + Alo*Whi, error ~2^-16.
__global__ __launch_bounds__(512, 2)
void lstm_rec_mfma(const float* __restrict__ xp,
                   const float* __restrict__ h0, const float* __restrict__ c0,
                   const float* __restrict__ Whh, float* __restrict__ out)
{
    __shared__ __align__(16) unsigned short h_lds[2][2][16][128]; // [buf][hi/lo][row][k]

    const int tid  = threadIdx.x;
    const int bb0  = blockIdx.x * 16;       // batch base
    const int wid  = tid >> 6;              // wave 0..7
    const int lane = tid & 63;
    const int col  = lane & 15;
    const int lgrp = lane >> 4;             // 0..3
    const int j    = wid * 16 + col;        // hidden index 0..127

    // ---- W_hh -> register fragments, hi/lo bf16 split ----
    // B[k][n] = Whh[n][k]; B-frag: lane holds n=col(within tile), k=lgrp*8+e.
    bf16x8 Whi[4][4], Wlo[4][4];            // [gate q][kk]
    #pragma unroll
    for (int q = 0; q < 4; ++q) {
        const float* wr = &Whh[(size_t)(q * 128 + j) * E];
        #pragma unroll
        for (int kk = 0; kk < 4; ++kk) {
            const float4 w0 = *reinterpret_cast<const float4*>(&wr[kk * 32 + lgrp * 8]);
            const float4 w1 = *reinterpret_cast<const float4*>(&wr[kk * 32 + lgrp * 8 + 4]);
            const float wv[8] = {w0.x, w0.y, w0.z, w0.w, w1.x, w1.y, w1.z, w1.w};
            #pragma unroll
            for (int e = 0; e < 8; ++e) {
                const __bf16 hi = (__bf16)wv[e];
                Whi[q][kk][e] = hi;
                Wlo[q][kk][e] = (__bf16)(wv[e] - (float)hi);
            }
        }
    }

    // ---- c state: lane owns rows lgrp*4+r at hidden col j ----
    float c[4];
    #pragma unroll
    for (int r = 0; r < 4; ++r)
        c[r] = c0[(size_t)(bb0 + lgrp * 4 + r) * E + j];

    // ---- h0 -> h_lds[0] (hi/lo, rotation swizzle (k + row*8) & 127) ----
    #pragma unroll
    for (int s = 0; s < 4; ++s) {
        const int id  = tid + s * 512;      // 0..2047
        const int row = id >> 7;
        const int k   = id & 127;
        const float hv = h0[(size_t)(bb0 + row) * E + k];
        const unsigned short hb = f2bf_bits(hv);
        const unsigned short lb = f2bf_bits(hv - bfbits2f(hb));
        const int sidx = (k + row * 8) & 127;
        h_lds[0][0][row][sidx] = hb;
        h_lds[0][1][row][sidx] = lb;
    }

    // ---- xp prefetch for step 0 (C-layout: row=lgrp*4+r, col=j per tile q) ----
    float xpre[4][4];
    #pragma unroll
    for (int q = 0; q < 4; ++q)
        #pragma unroll
        for (int r = 0; r < 4; ++r)
            xpre[q][r] = xp[(size_t)(bb0 + lgrp * 4 + r) * G4E + q * 128 + j];

    __syncthreads();

    int cur = 0;
    for (int step = 0; step < T_STEPS; ++step) {
        // acc init = xp (bias already folded in by phase 1)
        f32x4 acc[4];
        #pragma unroll
        for (int q = 0; q < 4; ++q)
            #pragma unroll
            for (int r = 0; r < 4; ++r)
                acc[q][r] = xpre[q][r];

        // A-fragments: lane row = lane&15, k = kk*32 + lgrp*8 + e
        bf16x8 Ahi[4], Alo[4];
        const int arow = col;
        #pragma unroll
        for (int kk = 0; kk < 4; ++kk) {
            const int idx = (kk * 32 + lgrp * 8 + arow * 8) & 127;
            Ahi[kk] = *reinterpret_cast<const bf16x8*>(&h_lds[cur][0][arow][idx]);
            Alo[kk] = *reinterpret_cast<const bf16x8*>(&h_lds[cur][1][arow][idx]);
        }

        // prefetch next step's xp (hidden under MFMA + update)
        {
            const int nstep = (step + 1 < T_STEPS) ? step + 1 : 0;
            #pragma unroll
            for (int q = 0; q < 4; ++q)
                #pragma unroll
                for (int r = 0; r < 4; ++r)
                    xpre[q][r] = xp[((size_t)nstep * BATCH + bb0 + lgrp * 4 + r) * G4E
                                    + q * 128 + j];
        }

        // 3-product split MFMA: h.W = Ahi*Whi + Ahi*Wlo + Alo*Whi (+O(2^-18))
        #pragma unroll
        for (int kk = 0; kk < 4; ++kk) {
            #pragma unroll
            for (int q = 0; q < 4; ++q) {
                acc[q] = __builtin_amdgcn_mfma_f32_16x16x32_bf16(Ahi[kk], Whi[q][kk], acc[q], 0, 0, 0);
                acc[q] = __builtin_amdgcn_mfma_f32_16x16x32_bf16(Ahi[kk], Wlo[q][kk], acc[q], 0, 0, 0);
                acc[q] = __builtin_amdgcn_mfma_f32_16x16x32_bf16(Alo[kk], Whi[q][kk], acc[q], 0, 0, 0);
            }
        }

        // gates -> c,h -> output + next h tile (all lane-local)
        const int nxt = cur ^ 1;
        #pragma unroll
        for (int r = 0; r < 4; ++r) {
            const float gi = sigmoidf_fast(acc[0][r]);
            const float gf = sigmoidf_fast(acc[1][r]);
            const float gg = tanhf_fast(acc[2][r]);
            const float go = sigmoidf_fast(acc[3][r]);
            const float cn = fmaf(gf, c[r], gi * gg);
            c[r] = cn;
            const float h = go * tanhf_fast(cn);
            const int row = lgrp * 4 + r;
            out[((size_t)step * BATCH + bb0 + row) * E + j] = softplusf(h);
            const unsigned short hb = f2bf_bits(h);
            const unsigned short lb = f2bf_bits(h - bfbits2f(hb));
            const int sidx = (j + row * 8) & 127;
            h_lds[nxt][0][row][sidx] = hb;
            h_lds[nxt][1][row][sidx] = lb;
        }
        __syncthreads();
        cur ^= 1;
    }
}

// ---------- launcher ----------
extern "C" void kernel_launch(void* const* d_in, const int* in_sizes, int n_in,
                              void* d_out, int out_size, void* d_ws, size_t ws_size,
                              hipStream_t stream)
{
    const float* x   = (const float*)d_in[0];
    const float* h0  = (const float*)d_in[1];
    const float* c0  = (const float*)d_in[2];
    const float* Wih = (const float*)d_in[3];
    const float* Whh = (const float*)d_in[4];
    const float* bih = (const float*)d_in[5];
    const float* bhh = (const float*)d_in[6];

    float* xp = (float*)d_ws;   // f32 xp: 536 MB (fits, proven R1)

    dim3 g1(G4E / 128, (T_STEPS * BATCH) / 128);  // (4, 2048)
    xproj_gemm<<<g1, dim3(256), 0, stream>>>(x, Wih, bih, bhh, xp);

    lstm_rec_mfma<<<dim3(BATCH / 16), dim3(512), 0, stream>>>(
        xp, h0, c0, Whh, (float*)d_out);
}